// Round 4
// baseline (126.690 us; speedup 1.0000x reference)
//
#include <hip/hip_runtime.h>
#include <hip/hip_bf16.h>

// PositionalBias: pbv[n,j,h,d] = sum_{l=1..2046} w[h,|j-l|] * v[n,l,h,d]  (j in 1..2046, else 0)
//                 z_pb[l,h]    = sum_{j=1..2046} w[h,|l-j|]               (l in 1..2046, else 0)
// B=4, S=2048, H=12, D=64. Outputs fp32: pbv (6291456) then z_pb (24576).

typedef short short8 __attribute__((ext_vector_type(8)));   // 8 x bf16 bits (4 VGPRs)
typedef float floatx4 __attribute__((ext_vector_type(4)));  // MFMA accumulator

#define TL 2280   // table length per copy; 2280/2 % 32 = 20 = 4*odd -> 8 copies hit distinct banks

__device__ __forceinline__ unsigned short f2bf(float f) {
  union { __hip_bfloat16 b; unsigned short u; } cv;
  cv.b = __float2bfloat16(f);  // RNE
  return cv.u;
}

// ---------------- prep: v transpose (+ zpb in extra blocks) -------------------------------------
// vb[h][nd][l] bf16 (plain layout), zero l=0,2047.
__global__ __launch_bounds__(256) void prep_kernel(const float* __restrict__ v,
                                                   const float* __restrict__ w,
                                                   unsigned short* __restrict__ vb,
                                                   float* __restrict__ zout) {
  __shared__ float smem[64 * 65];
  const int lt = blockIdx.x;   // 0..32; 32 => zpb block
  const int h  = blockIdx.y;   // 12
  const int n  = blockIdx.z;   // 4
  const int tid = threadIdx.x;

  if (lt == 32) {               // ---- zpb: z[i+1] = P[i] + P[2045-i] - w[h,0] ----
    if (n != 0) return;
    float* wv  = smem;          // [2048]
    float* pfx = smem + 2048;   // [2048]
    __shared__ float wsum[4];
    const float* wh = w + (size_t)h * 2048;
    for (int i = tid; i < 2048; i += 256) wv[i] = (i < 2046) ? wh[i] : 0.f;
    __syncthreads();
    const int base = tid * 8;
    float run0 = 0.f;
    #pragma unroll
    for (int k = 0; k < 8; ++k) run0 += wv[base + k];
    float x = run0;
    #pragma unroll
    for (int d = 1; d < 64; d <<= 1) {
      float y = __shfl_up(x, d);
      if ((tid & 63) >= d) x += y;
    }
    if ((tid & 63) == 63) wsum[tid >> 6] = x;
    __syncthreads();
    const int wid = tid >> 6;
    float woff = 0.f;
    #pragma unroll
    for (int u = 0; u < 3; ++u) { float t = wsum[u]; if (u < wid) woff += t; }
    float pr = x + woff - run0;
    #pragma unroll
    for (int k = 0; k < 8; ++k) { pr += wv[base + k]; pfx[base + k] = pr; }
    __syncthreads();
    for (int i = tid; i < 2046; i += 256) {
      float z = pfx[i] + pfx[2045 - i] - wv[0];
      zout[(size_t)(i + 1) * 12 + h] = z;
    }
    if (tid == 0) { zout[h] = 0.f; zout[(size_t)2047 * 12 + h] = 0.f; }
    return;
  }

  // ---- transpose tile: 64 l x 64 d ----
  float (*tile)[65] = (float(*)[65])smem;
  const int l0 = lt * 64;
  {
    const int row = tid >> 2;          // 0..63 (l within tile)
    const int cq  = (tid & 3) * 16;    // 4 float4 per thread
    const float* src = v + (((size_t)n * 2048 + (l0 + row)) * 12 + h) * 64 + cq;
    #pragma unroll
    for (int u = 0; u < 4; ++u) {
      float4 f4 = *(const float4*)(src + u * 4);
      tile[row][cq + u * 4 + 0] = f4.x;
      tile[row][cq + u * 4 + 1] = f4.y;
      tile[row][cq + u * 4 + 2] = f4.z;
      tile[row][cq + u * 4 + 3] = f4.w;
    }
  }
  __syncthreads();
  {
    const int d = tid >> 2;            // 0..63
    const int q = tid & 3;             // 0..3 (16 l each)
    const int nd = n * 64 + d;
    unsigned short buf[16] __attribute__((aligned(16)));
    #pragma unroll
    for (int jj = 0; jj < 16; ++jj) {
      int l = l0 + q * 16 + jj;
      float f = tile[q * 16 + jj][d];
      buf[jj] = (l == 0 || l == 2047) ? (unsigned short)0 : f2bf(f);
    }
    unsigned short* dst = vb + ((size_t)h * 256 + nd) * 2048 + l0 + q * 16;
    *(uint4*)dst       = *(const uint4*)&buf[0];
    *(uint4*)(dst + 8) = *(const uint4*)&buf[8];
  }
}

// ---------------- main Toeplitz GEMM: barrier-free K-loop ---------------------------------------
// Block = 128j x 64nd; each of 4 waves owns a PRIVATE 128j x 16nd strip.
//  - B-fragments: per-lane 16B global loads straight to VGPR (L2-resident vb), pipelined 1 ahead.
//  - A-fragments: Toeplitz table in LDS, 8 pre-shifted copies -> one aligned ds_read_b128 each;
//    sliding 10-frag register window, 4 fresh reads/iter.
//  - No __syncthreads in the K-loop (only one after the table build): waves free-run.
// Grid (48=(h,ndt), 16=jt): the 16 jt-blocks sharing a vb slice are 48 apart in dispatch order
// -> same XCD under %8 round-robin -> slice cached in that XCD's L2 (1.5 MB working set).
__global__ __launch_bounds__(256, 3) void gemm_kernel(const float* __restrict__ w,
                                                      const unsigned short* __restrict__ vb,
                                                      float* __restrict__ out) {
  __shared__ __attribute__((aligned(16))) short Tls[8 * TL];  // 36.5 KB

  const int ndt = blockIdx.x & 3;
  const int h   = blockIdx.x >> 2;    // 12
  const int jt  = blockIdx.y;         // 16
  const int tid = threadIdx.x;
  const int lane = tid & 63;
  const int wid  = tid >> 6;
  const int lm = lane & 15, quad = lane >> 4;
  const int jb = jt * 128;
  const int strip = ndt * 64 + wid * 16;   // wave's private 16-nd strip

  // B row pointer for this lane: row = strip+lm (nd), col base = quad*8 (k within 32-chunk)
  const unsigned short* brow = vb + ((size_t)h * 256 + strip + lm) * 2048 + quad * 8;

  // issue t=0 B loads before the table build (latency hidden under build)
  short8 b0 = *(const short8*)(brow);        // kc=0
  short8 b1 = *(const short8*)(brow + 32);   // kc=1

  // build reversed, 8x-shifted kernel table: T_c[p] = w_ext[127 + jb - p - c]
  const float* wh = w + (size_t)h * 2048;
  for (int g = tid; g < 8 * (TL / 8); g += 256) {
    int c  = g / (TL / 8);
    int p8 = (g - c * (TL / 8)) * 8;
    unsigned short buf[8] __attribute__((aligned(16)));
    #pragma unroll
    for (int i = 0; i < 8; ++i) {
      int t = 127 + jb - (p8 + i) - c;
      int a = t < 0 ? -t : t;
      buf[i] = (a <= 2045) ? f2bf(wh[a]) : (unsigned short)0;
    }
    *(short8*)&Tls[c * TL + p8] = *(const short8*)buf;
  }
  __syncthreads();   // the only block-wide sync

  // A-frag: value[i] = w_ext[j - l], j = jb + ma*16 + lm, l = l0 + kc*32 + quad*8 + i
  // p0 = l0 + 16*g + pbase, g = 2*kc - ma in [-7,2]; aligned b128 from shifted copy (p0 & 7).
  const int pbase = 127 + quad * 8 - lm;
  auto load_af = [&](int p0) -> short8 {
    int c = p0 & 7;
    return *(const short8*)&Tls[c * TL + (p0 - c)];
  };

  short8 afr[10];                      // afr[i] holds diagonal g = i-7
  #pragma unroll
  for (int i = 0; i < 10; ++i) afr[i] = load_af((i - 7) * 16 + pbase);

  floatx4 acc[8];
  #pragma unroll
  for (int ma = 0; ma < 8; ++ma) acc[ma] = (floatx4){0.f, 0.f, 0.f, 0.f};

  #pragma unroll 4
  for (int t = 0; t < 32; ++t) {
    const int l0 = t * 64;
    // prefetch next iter's B (register pipeline; clamp at tail re-reads t=31: harmless)
    const int tn = (t < 31) ? t + 1 : 31;
    short8 nb0 = *(const short8*)(brow + tn * 64);
    short8 nb1 = *(const short8*)(brow + tn * 64 + 32);
    // prefetch next iter's fresh A diagonals (g = -1,0,1,2 at l0+64)
    short8 na0 = load_af(l0 + 64 - 16 + pbase);
    short8 na1 = load_af(l0 + 64      + pbase);
    short8 na2 = load_af(l0 + 64 + 16 + pbase);
    short8 na3 = load_af(l0 + 64 + 32 + pbase);

    #pragma unroll
    for (int ma = 0; ma < 8; ++ma)   // kc=0: g = -ma  -> idx 7-ma
      acc[ma] = __builtin_amdgcn_mfma_f32_16x16x32_bf16(afr[7 - ma], b0, acc[ma], 0, 0, 0);
    #pragma unroll
    for (int ma = 0; ma < 8; ++ma)   // kc=1: g = 2-ma -> idx 9-ma
      acc[ma] = __builtin_amdgcn_mfma_f32_16x16x32_bf16(afr[9 - ma], b1, acc[ma], 0, 0, 0);

    // slide the window by 4 (l0 += 64 <=> g -= 4)
    #pragma unroll
    for (int i = 0; i < 6; ++i) afr[i] = afr[i + 4];
    afr[6] = na0; afr[7] = na1; afr[8] = na2; afr[9] = na3;
    b0 = nb0; b1 = nb1;
  }

  // epilogue: D row = quad*4 + r (j), col = lm (nd); zero rows j=0 and j=2047
  const int ndv = strip + lm;
  const int n = ndv >> 6, d = ndv & 63;
  float* obase = out + (size_t)n * 1572864 + (size_t)h * 64 + d;
  #pragma unroll
  for (int ma = 0; ma < 8; ++ma) {
    floatx4 c = acc[ma];
    #pragma unroll
    for (int r = 0; r < 4; ++r) {
      int j = jb + ma * 16 + quad * 4 + r;
      float val = (j == 0 || j == 2047) ? 0.f : c[r];
      obase[(size_t)j * 768] = val;
    }
  }
}

extern "C" void kernel_launch(void* const* d_in, const int* in_sizes, int n_in,
                              void* d_out, int out_size, void* d_ws, size_t ws_size,
                              hipStream_t stream) {
  const float* v = (const float*)d_in[0];   // (4,2048,12,64) fp32
  const float* w = (const float*)d_in[1];   // (12,2048) fp32
  float* out = (float*)d_out;               // pbv (6291456) + z_pb (24576) fp32
  unsigned short* vb = (unsigned short*)d_ws;  // 12*256*2048 bf16 = 12.58 MB

  prep_kernel<<<dim3(33, 12, 4), 256, 0, stream>>>(v, w, vb, out + 6291456);
  gemm_kernel<<<dim3(48, 16, 1), 256, 0, stream>>>(w, vb, out);
}